// Round 9
// baseline (194.830 us; speedup 1.0000x reference)
//
#include <hip/hip_runtime.h>

// N=50000, E=800000 (per relation), D=128, O=128, fp32 in/out.
// out = relu( spmm(adj1, X@W1) + spmm(adj2, X@W2) )
//      = relu( spmm(adj1, X) @ W1 + spmm(adj2, X) @ W2 )   [associativity]
//
// Pipeline (all on `stream`, graph-capture safe):
//   convbin1: [blocks 0..2047]  level-1 bin: edges -> 13 super-buckets
//             (4096 rows), rel0 from bottom / rel1 from top of each region,
//             LDS write-combined (26 keys x 64 slots, ~512B runs).
//             [blocks 2048..2303] convert: Xb = bf16(X), Wt = bf16(W^T).
//   bin2:     per super: re-bin into 64-row buckets (64 keys x 32 slots),
//             pack {val:f32 | col:16 | rel:1 | rowLocal:6}.
//   agg:      persistent work-stealing blocks (2048): per 16-row quarter,
//             single-pass scatter into fixed-stride LDS lists keyed by
//             (rowLocal,rel) [32 segs x 64 slots], then per-seg register
//             gather sum(val * Xb[col]), bf16 agg store.
//   gemm:     out = relu( agg0 @ W1 + agg1 @ W2 ) via 16x16x32 bf16 MFMA.

typedef __attribute__((ext_vector_type(4))) float     f32x4;
typedef __attribute__((ext_vector_type(8))) short     bf16x8;

#define NB      782     // 64-row buckets: ceil(50000/64)
#define NSUP    13      // 4096-row super-buckets
#define SB1     64      // LDS slots per (super,rel) in level-1 bin
// Per-super edge count: supers 0..11 cover 4096/50000 = 8.192% of 1.6M edges
// -> mean 131072 (rel0+rel1 combined; they share the region from opposite
// ends). sigma = sqrt(1.6e6*0.0819*0.918) ~= 347. SCAPS = mean + ~47 sigma.
// (Round-8 bug: SCAPS was set to the MEAN -> ends collided ~50% of supers.)
#define SCAPS   147456
#define B2BLK   79      // blocks per super in bin2
#define BCAP    2560    // capacity per 64-row bucket (mean 2048, ~11 sigma)
#define SCAP    64      // per (row,rel) seg capacity (mean 16; P(>64)~2e-18)
#define BIN1G   2048    // level-1 bin blocks
#define CONVG   256     // convert blocks

static __device__ __forceinline__ unsigned short f2bf(float f) {
    unsigned u = __float_as_uint(f);
    u += 0x7FFF + ((u >> 16) & 1);           // round-to-nearest-even
    return (unsigned short)(u >> 16);
}

// ---------------------------------------------------------------------------
// Fused: level-1 bin (blocks < BIN1G) + convert (blocks >= BIN1G).
// Level-1 pack = {val:f32:32 | col:16 | row:16}; rel encoded by region end.
// ---------------------------------------------------------------------------
__global__ __launch_bounds__(256) void convbin1_kernel(
    const float* __restrict__ X,
    const float* __restrict__ W1, const float* __restrict__ W2,
    const int* __restrict__ rows1, const int* __restrict__ cols1, const float* __restrict__ vals1,
    const int* __restrict__ rows2, const int* __restrict__ cols2, const float* __restrict__ vals2,
    unsigned short* __restrict__ Xb, unsigned short* __restrict__ Wt,
    int* __restrict__ gcur1, unsigned long long* __restrict__ super_tmp,
    int E, int n)
{
    if (blockIdx.x >= BIN1G) {
        // ---- convert role ----
        const int stride = CONVG * 256;
        const int nW = 2 * 128 * 128;
        const int nX = n * 32;               // float4 count
        const int total = nW + nX;
        for (int g = (blockIdx.x - BIN1G) * 256 + threadIdx.x; g < total; g += stride) {
            if (g < nW) {
                const int rel = g >> 14;
                const int o   = (g >> 7) & 127;
                const int k   = g & 127;
                const float* W = rel ? W2 : W1;
                Wt[g] = f2bf(W[k * 128 + o]);
            } else {
                const int i = g - nW;
                const float4 v = ((const float4*)X)[i];
                ushort4 b;
                b.x = f2bf(v.x); b.y = f2bf(v.y); b.z = f2bf(v.z); b.w = f2bf(v.w);
                ((ushort4*)Xb)[i] = b;
            }
        }
        return;
    }

    // ---- level-1 bin role ----
    __shared__ unsigned long long stage[2 * NSUP][SB1];
    __shared__ int scnt[2 * NSUP];

    for (int i = threadIdx.x; i < 2 * NSUP; i += 256) scnt[i] = 0;
    __syncthreads();

    const int total = 2 * E;
    for (int g = blockIdx.x * 256 + threadIdx.x; g < total; g += BIN1G * 256) {
        int r, col, rel; float v;
        if (g < E) { r = rows1[g]; col = cols1[g]; rel = 0; v = vals1[g]; }
        else       { int e = g - E; r = rows2[e]; col = cols2[e]; rel = 1; v = vals2[e]; }

        const int s   = r >> 12;
        const int key = s * 2 + rel;
        const unsigned long long pack =
            (unsigned long long)((unsigned)(r & 0xFFFF) | ((unsigned)col << 16))
            | ((unsigned long long)__float_as_uint(v) << 32);

        const int pos = atomicAdd(&scnt[key], 1);
        if (pos < SB1) {
            stage[key][pos] = pack;
        } else {                                  // rare overflow: direct write
            if (rel == 0) {
                int gp = atomicAdd(&gcur1[2 * s], 1);
                if (gp < SCAPS) super_tmp[(size_t)s * SCAPS + gp] = pack;
            } else {
                int gp = atomicAdd(&gcur1[2 * s + 1], 1);
                if (gp < SCAPS) super_tmp[(size_t)s * SCAPS + (SCAPS - 1 - gp)] = pack;
            }
        }
    }
    __syncthreads();

    for (int key = threadIdx.x; key < 2 * NSUP; key += 256) {
        int k = scnt[key]; if (k > SB1) k = SB1;
        if (k > 0) {
            const int s = key >> 1, rel = key & 1;
            if (rel == 0) {
                int base = atomicAdd(&gcur1[2 * s], k);
                for (int i = 0; i < k; ++i) {
                    int gp = base + i;
                    if (gp < SCAPS) super_tmp[(size_t)s * SCAPS + gp] = stage[key][i];
                }
            } else {
                int base = atomicAdd(&gcur1[2 * s + 1], k);
                for (int i = 0; i < k; ++i) {
                    int gp = base + i;
                    if (gp < SCAPS) super_tmp[(size_t)s * SCAPS + (SCAPS - 1 - gp)] = stage[key][i];
                }
            }
        }
    }
}

// ---------------------------------------------------------------------------
// Level-2 bin: block (super s, slice bi). Reads rel0 range [0, lo) ascending
// and rel1 range [SCAPS-hi, SCAPS) descending; re-bins into 64-row buckets.
// Level-2 pack = {val:f32 | col:16 | rel:1 | rowLocal:6} (agg's format).
// ---------------------------------------------------------------------------
__global__ __launch_bounds__(256) void bin2_kernel(
    const int* __restrict__ gcur1,
    const unsigned long long* __restrict__ super_tmp,
    int* __restrict__ gcur2, unsigned long long* __restrict__ edges_tmp,
    int n)
{
    __shared__ unsigned long long stage[64][32];
    __shared__ int scnt[64];

    const int s  = blockIdx.x / B2BLK;
    const int bi = blockIdx.x % B2BLK;
    const int tid = threadIdx.x;

    for (int i = tid; i < 64; i += 256) scnt[i] = 0;
    __syncthreads();

    int lo = gcur1[2 * s];     if (lo > SCAPS) lo = SCAPS;
    int hi = gcur1[2 * s + 1]; if (hi > SCAPS) hi = SCAPS;
    const unsigned long long* reg = super_tmp + (size_t)s * SCAPS;

    #pragma unroll
    for (int rel = 0; rel < 2; ++rel) {
        const int cnt = rel ? hi : lo;
        for (int k = bi * 256 + tid; k < cnt; k += B2BLK * 256) {
            const unsigned long long p = rel ? reg[SCAPS - 1 - k] : reg[k];
            const unsigned lo32 = (unsigned)p;
            const int row = (int)(lo32 & 0xFFFFu);
            const int col = (int)(lo32 >> 16);
            const unsigned long long pack =
                (unsigned long long)((unsigned)(row & 63) | ((unsigned)rel << 6) | ((unsigned)col << 7))
                | (p & 0xFFFFFFFF00000000ull);

            const int bl  = (row >> 6) & 63;
            const int pos = atomicAdd(&scnt[bl], 1);
            if (pos < 32) {
                stage[bl][pos] = pack;
            } else {
                const int b = row >> 6;
                int gp = atomicAdd(&gcur2[b], 1);
                if (gp < BCAP) edges_tmp[(size_t)b * BCAP + gp] = pack;
            }
        }
        // flush between rel passes so stage slots recycle
        __syncthreads();
        for (int bl = tid; bl < 64; bl += 256) {
            int k = scnt[bl]; if (k > 32) k = 32;
            if (k > 0) {
                const int b = (s << 6) + bl;
                int base = atomicAdd(&gcur2[b], k);
                for (int i = 0; i < k; ++i)
                    if (base + i < BCAP)
                        edges_tmp[(size_t)b * BCAP + base + i] = stage[bl][i];
            }
            scnt[bl] = 0;
        }
        __syncthreads();
    }
}

// ---------------------------------------------------------------------------
// Agg: persistent work-stealing blocks. Chunk = 16-row quarter-bucket:
// single-pass scatter into fixed-stride LDS lists (seg = (rowLocal&15)*2+rel),
// then per-seg register gather from Xb; bf16 agg store.
// ---------------------------------------------------------------------------
__global__ __launch_bounds__(256) void agg_kernel(
    const int* __restrict__ gcur2,
    const unsigned long long* __restrict__ edges_tmp,
    const unsigned short* __restrict__ Xb,
    unsigned short* __restrict__ agg,
    int* __restrict__ wctr, int n)
{
    __shared__ unsigned long long lists[32 * SCAP];
    __shared__ int cnt[32];
    __shared__ int chunk_s;

    const int tid = threadIdx.x;
    const int NQ = (n + 15) >> 4;            // 3125 quarters (n=50000 exact)

    for (;;) {
        __syncthreads();                      // protect lists/cnt/chunk reuse
        if (tid == 0) chunk_s = atomicAdd(wctr, 1);
        __syncthreads();
        const int c = chunk_s;
        if (c >= NQ) return;

        const int b = c >> 2;
        const int q = c & 3;
        const int rowbase = c * 16;

        int sz = gcur2[b]; if (sz > BCAP) sz = BCAP;
        const unsigned long long* ebase = edges_tmp + (size_t)b * BCAP;

        if (tid < 32) cnt[tid] = 0;
        __syncthreads();

        // Single pass: filter quarter, append to per-seg list.
        for (int e = tid; e < sz; e += 256) {
            const unsigned long long p = ebase[e];
            const unsigned lo = (unsigned)p;
            const int rl = (int)(lo & 63u);
            if ((rl >> 4) == q) {
                const int seg = ((rl & 15) << 1) | ((lo >> 6) & 1);
                const int pos = atomicAdd(&cnt[seg], 1);
                if (pos < SCAP) lists[seg * SCAP + pos] = p;
            }
        }
        __syncthreads();

        // Gather: 8 groups x 32 lanes; lane owns a 4-col slice (8B bf16).
        const int lane = tid & 31;
        const int grp  = tid >> 5;
        for (int seg = grp; seg < 32; seg += 8) {
            const int row = rowbase + (seg >> 1);
            if (row >= n) continue;
            const int rel = seg & 1;
            int m = cnt[seg]; if (m > SCAP) m = SCAP;
            const unsigned long long* lst = &lists[seg * SCAP];
            float4 acc = make_float4(0.f, 0.f, 0.f, 0.f);

            int e = 0;
            for (; e + 4 <= m; e += 4) {
                const unsigned long long p0 = lst[e + 0];
                const unsigned long long p1 = lst[e + 1];
                const unsigned long long p2 = lst[e + 2];
                const unsigned long long p3 = lst[e + 3];
                const ushort4 x0 = *(const ushort4*)&Xb[(size_t)(((unsigned)p0 >> 7) & 0xFFFFu) * 128 + lane * 4];
                const ushort4 x1 = *(const ushort4*)&Xb[(size_t)(((unsigned)p1 >> 7) & 0xFFFFu) * 128 + lane * 4];
                const ushort4 x2 = *(const ushort4*)&Xb[(size_t)(((unsigned)p2 >> 7) & 0xFFFFu) * 128 + lane * 4];
                const ushort4 x3 = *(const ushort4*)&Xb[(size_t)(((unsigned)p3 >> 7) & 0xFFFFu) * 128 + lane * 4];
                const float v0 = __uint_as_float((unsigned)(p0 >> 32));
                const float v1 = __uint_as_float((unsigned)(p1 >> 32));
                const float v2 = __uint_as_float((unsigned)(p2 >> 32));
                const float v3 = __uint_as_float((unsigned)(p3 >> 32));
                acc.x = fmaf(v0, __uint_as_float((unsigned)x0.x << 16), acc.x);
                acc.y = fmaf(v0, __uint_as_float((unsigned)x0.y << 16), acc.y);
                acc.z = fmaf(v0, __uint_as_float((unsigned)x0.z << 16), acc.z);
                acc.w = fmaf(v0, __uint_as_float((unsigned)x0.w << 16), acc.w);
                acc.x = fmaf(v1, __uint_as_float((unsigned)x1.x << 16), acc.x);
                acc.y = fmaf(v1, __uint_as_float((unsigned)x1.y << 16), acc.y);
                acc.z = fmaf(v1, __uint_as_float((unsigned)x1.z << 16), acc.z);
                acc.w = fmaf(v1, __uint_as_float((unsigned)x1.w << 16), acc.w);
                acc.x = fmaf(v2, __uint_as_float((unsigned)x2.x << 16), acc.x);
                acc.y = fmaf(v2, __uint_as_float((unsigned)x2.y << 16), acc.y);
                acc.z = fmaf(v2, __uint_as_float((unsigned)x2.z << 16), acc.z);
                acc.w = fmaf(v2, __uint_as_float((unsigned)x2.w << 16), acc.w);
                acc.x = fmaf(v3, __uint_as_float((unsigned)x3.x << 16), acc.x);
                acc.y = fmaf(v3, __uint_as_float((unsigned)x3.y << 16), acc.y);
                acc.z = fmaf(v3, __uint_as_float((unsigned)x3.z << 16), acc.z);
                acc.w = fmaf(v3, __uint_as_float((unsigned)x3.w << 16), acc.w);
            }
            for (; e < m; ++e) {
                const unsigned long long p = lst[e];
                const ushort4 xv = *(const ushort4*)&Xb[(size_t)(((unsigned)p >> 7) & 0xFFFFu) * 128 + lane * 4];
                const float v  = __uint_as_float((unsigned)(p >> 32));
                acc.x = fmaf(v, __uint_as_float((unsigned)xv.x << 16), acc.x);
                acc.y = fmaf(v, __uint_as_float((unsigned)xv.y << 16), acc.y);
                acc.z = fmaf(v, __uint_as_float((unsigned)xv.z << 16), acc.z);
                acc.w = fmaf(v, __uint_as_float((unsigned)xv.w << 16), acc.w);
            }

            ushort4 o;
            o.x = f2bf(acc.x); o.y = f2bf(acc.y); o.z = f2bf(acc.z); o.w = f2bf(acc.w);
            *(ushort4*)&agg[((size_t)rel * n + row) * 128 + lane * 4] = o;
        }
    }
}

// ---------------------------------------------------------------------------
// GEMM epilogue: out = relu( agg0 @ W1 + agg1 @ W2 ), bf16 MFMA, fp32 out.
// 32-row tiles. A-frag: row = lane&15, k = (lane>>4)*8 + j. C/D: col=lane&15,
// row=(lane>>4)*4+reg  [m89-verified].
// ---------------------------------------------------------------------------
__global__ __launch_bounds__(256) void gemm_relu_kernel(
    const unsigned short* __restrict__ agg,
    const unsigned short* __restrict__ Wt,
    float* __restrict__ out, int n)
{
    const int lane = threadIdx.x & 63;
    const int w    = threadIdx.x >> 6;
    const int colbase = w * 32;
    const int l15 = lane & 15;
    const int lhi = lane >> 4;

    bf16x8 bfrag[2][2][4];                   // [rel][ct][ks]
    #pragma unroll
    for (int rel = 0; rel < 2; ++rel) {
        const unsigned short* Wr = Wt + rel * 16384;
        #pragma unroll
        for (int ct = 0; ct < 2; ++ct) {
            const int o = colbase + ct * 16 + l15;
            #pragma unroll
            for (int ks = 0; ks < 4; ++ks)
                bfrag[rel][ct][ks] = *(const bf16x8*)&Wr[o * 128 + ks * 32 + lhi * 8];
        }
    }

    const int row0 = blockIdx.x * 32;
    const f32x4 zero = {0.f, 0.f, 0.f, 0.f};

    #pragma unroll
    for (int rt = 0; rt < 2; ++rt) {
        const int r0 = row0 + rt * 16;
        int ra = r0 + l15; if (ra >= n) ra = n - 1;   // clamp OOB reads
        bf16x8 af0[4], af1[4];
        #pragma unroll
        for (int ks = 0; ks < 4; ++ks) {
            af0[ks] = *(const bf16x8*)&agg[(size_t)ra * 128 + ks * 32 + lhi * 8];
            af1[ks] = *(const bf16x8*)&agg[((size_t)n + ra) * 128 + ks * 32 + lhi * 8];
        }

        f32x4 acc[2];
        acc[0] = zero; acc[1] = zero;
        #pragma unroll
        for (int ks = 0; ks < 4; ++ks) {
            acc[0] = __builtin_amdgcn_mfma_f32_16x16x32_bf16(af0[ks], bfrag[0][0][ks], acc[0], 0, 0, 0);
            acc[1] = __builtin_amdgcn_mfma_f32_16x16x32_bf16(af0[ks], bfrag[0][1][ks], acc[1], 0, 0, 0);
            acc[0] = __builtin_amdgcn_mfma_f32_16x16x32_bf16(af1[ks], bfrag[1][0][ks], acc[0], 0, 0, 0);
            acc[1] = __builtin_amdgcn_mfma_f32_16x16x32_bf16(af1[ks], bfrag[1][1][ks], acc[1], 0, 0, 0);
        }

        #pragma unroll
        for (int ct = 0; ct < 2; ++ct) {
            const int col = colbase + ct * 16 + l15;
            #pragma unroll
            for (int j = 0; j < 4; ++j) {
                const int r = r0 + lhi * 4 + j;
                if (r < n) out[(size_t)r * 128 + col] = fmaxf(acc[ct][j], 0.f);
            }
        }
    }
}

extern "C" void kernel_launch(void* const* d_in, const int* in_sizes, int n_in,
                              void* d_out, int out_size, void* d_ws, size_t ws_size,
                              hipStream_t stream)
{
    const float* X  = (const float*)d_in[0];
    const int*   r1 = (const int*)  d_in[1];
    const int*   c1 = (const int*)  d_in[2];
    const float* v1 = (const float*)d_in[3];
    const int*   r2 = (const int*)  d_in[4];
    const int*   c2 = (const int*)  d_in[5];
    const float* v2 = (const float*)d_in[6];
    const float* W1 = (const float*)d_in[7];
    const float* W2 = (const float*)d_in[8];
    float*       out = (float*)d_out;

    const int n = in_sizes[0] / 128;   // 50000
    const int E = in_sizes[1];         // 800000

    // Workspace layout:
    //   agg       : 2*n*128 bf16   (25.6 MB)  — super_tmp (15.3 MB) ALIASES
    //               this region: super_tmp dead before agg_kernel writes it.
    //   Xb        : n*128 bf16     (12.8 MB)
    //   Wt        : 2*128*128 bf16 (64 KB)
    //   edges_tmp : NB*BCAP u64    (16.0 MB), 256B-aligned
    //   gcur1[26] | gcur2[NB] | wctr[1]  (one contiguous memset)
    unsigned short* agg = (unsigned short*)d_ws;
    unsigned long long* super_tmp = (unsigned long long*)d_ws;   // alias
    unsigned short* Xb  = agg + (size_t)2 * n * 128;
    unsigned short* Wt  = Xb + (size_t)n * 128;
    unsigned long long* edges_tmp =
        (unsigned long long*)(((uintptr_t)(Wt + 2 * 128 * 128) + 255) & ~(uintptr_t)255);
    int* gcur1 = (int*)(edges_tmp + (size_t)NB * BCAP);
    int* gcur2 = gcur1 + 2 * NSUP;
    int* wctr  = gcur2 + NB;

    hipMemsetAsync(gcur1, 0, (2 * NSUP + NB + 1) * sizeof(int), stream);

    // level-1 bin + convert (fused, disjoint block ranges)
    convbin1_kernel<<<BIN1G + CONVG, 256, 0, stream>>>(
        X, W1, W2, r1, c1, v1, r2, c2, v2, Xb, Wt, gcur1, super_tmp, E, n);

    // level-2 bin: supers -> 64-row buckets
    bin2_kernel<<<NSUP * B2BLK, 256, 0, stream>>>(gcur1, super_tmp, gcur2, edges_tmp, n);

    // aggregate (persistent work-stealing)
    agg_kernel<<<2048, 256, 0, stream>>>(gcur2, edges_tmp, Xb, agg, wctr, n);

    // GEMM + ReLU epilogue
    gemm_relu_kernel<<<(n + 31) / 32, 256, 0, stream>>>(agg, Wt, out, n);
}

// Round 10
// 135.077 us; speedup vs baseline: 1.4424x; 1.4424x over previous
//
#include <hip/hip_runtime.h>

// N=50000, E=800000 (per relation), D=128, O=128, fp32 in/out.
// out = relu( spmm(adj1, X@W1) + spmm(adj2, X@W2) )
//      = relu( spmm(adj1, X) @ W1 + spmm(adj2, X) @ W2 )   [associativity]
//
// Pipeline (all on `stream`, graph-capture safe):
//   convbin: [blocks 0..511]  bin: edges -> 782 64-row buckets; block parity
//            selects bucket-HALF (391 LDS keys x 12 slots = 38KB -> 4
//            blocks/CU, 2x the old occupancy; each edge read twice).
//            Pack {val:f32 | col:16 | rel:1 | rowLocal:6}.
//            [blocks 512..767] convert: Xb = bf16(X), Wt = bf16(W^T).
//   agg:     one block per 8-row octant-chunk (grid 6250, static m204
//            XCD swizzle -> all 8 octants of a bucket on one XCD). Single
//            pass scatter into 16 fixed-stride LDS seg-lists, then per-seg
//            register gather sum(val * Xb[col]), bf16 agg store.
//            8.3KB LDS -> 8 blocks/CU (wave-capped), 3.05 rounds -> ~4% tail.
//   gemm:    out = relu( agg0 @ W1 + agg1 @ W2 ) via 16x16x32 bf16 MFMA.
//
// r9 lesson (measured): work-stealing agg destroyed XCD locality and added
// contended single-line atomics (54.7 -> 98.4 us). Static swizzled mapping
// restored; tail fixed by finer chunks instead.

typedef __attribute__((ext_vector_type(4))) float     f32x4;
typedef __attribute__((ext_vector_type(8))) short     bf16x8;

#define NB      782     // 64-row buckets: ceil(50000/64)
#define NBH     391     // buckets per half (bin stages one half per block)
#define BSLOTS  12      // LDS staging slots per bucket in bin (mean fill ~8)
#define BCAP    2560    // capacity per bucket (mean 2048, ~11 sigma slack)
#define SCAP    64      // per (row,rel) seg capacity (mean 16; P(>64)~1e-18)
#define BING    512     // bin blocks (256 slices x 2 halves)
#define CONVG   256     // convert blocks

static __device__ __forceinline__ unsigned short f2bf(float f) {
    unsigned u = __float_as_uint(f);
    u += 0x7FFF + ((u >> 16) & 1);           // round-to-nearest-even
    return (unsigned short)(u >> 16);
}

// ---------------------------------------------------------------------------
// Fused: bin (blocks < BING) + convert (blocks >= BING).
// ---------------------------------------------------------------------------
__global__ __launch_bounds__(256) void convbin_kernel(
    const float* __restrict__ X,
    const float* __restrict__ W1, const float* __restrict__ W2,
    const int* __restrict__ rows1, const int* __restrict__ cols1, const float* __restrict__ vals1,
    const int* __restrict__ rows2, const int* __restrict__ cols2, const float* __restrict__ vals2,
    unsigned short* __restrict__ Xb, unsigned short* __restrict__ Wt,
    int* __restrict__ gcur, unsigned long long* __restrict__ edges_tmp,
    int E, int n)
{
    if (blockIdx.x >= BING) {
        // ---- convert role ----
        const int stride = CONVG * 256;
        const int nW = 2 * 128 * 128;
        const int nX = n * 32;               // float4 count
        const int total = nW + nX;
        for (int g = (blockIdx.x - BING) * 256 + threadIdx.x; g < total; g += stride) {
            if (g < nW) {
                const int rel = g >> 14;
                const int o   = (g >> 7) & 127;
                const int k   = g & 127;
                const float* W = rel ? W2 : W1;
                Wt[g] = f2bf(W[k * 128 + o]);
            } else {
                const int i = g - nW;
                const float4 v = ((const float4*)X)[i];
                ushort4 b;
                b.x = f2bf(v.x); b.y = f2bf(v.y); b.z = f2bf(v.z); b.w = f2bf(v.w);
                ((ushort4*)Xb)[i] = b;
            }
        }
        return;
    }

    // ---- bin role: slice of edges, one bucket-half ----
    __shared__ unsigned long long stage[NBH][BSLOTS];
    __shared__ int scnt[NBH];

    const int slice = blockIdx.x >> 1;       // [0, 256)
    const int half  = blockIdx.x & 1;
    const int tid   = threadIdx.x;

    for (int i = tid; i < NBH; i += 256) scnt[i] = 0;
    __syncthreads();

    const int total = 2 * E;
    const int per   = (total + (BING / 2) - 1) / (BING / 2);   // 6250
    const int base  = slice * per;
    const int end   = min(base + per, total);

    for (int g = base + tid; g < end; g += 256) {
        int r, col, rel; float v;
        if (g < E) { r = rows1[g]; col = cols1[g]; rel = 0; v = vals1[g]; }
        else       { int e = g - E; r = rows2[e]; col = cols2[e]; rel = 1; v = vals2[e]; }

        const int b  = r >> 6;
        const int bh = (b >= NBH) ? 1 : 0;
        if (bh != half) continue;

        const int key = half ? b - NBH : b;
        const unsigned lo = (unsigned)(r & 63) | ((unsigned)rel << 6) | ((unsigned)col << 7);
        const unsigned long long pack =
            (unsigned long long)lo | ((unsigned long long)__float_as_uint(v) << 32);

        const int pos = atomicAdd(&scnt[key], 1);
        if (pos < BSLOTS) {
            stage[key][pos] = pack;
        } else {                                  // rare overflow: direct write
            int gp = atomicAdd(&gcur[b], 1);
            if (gp < BCAP) edges_tmp[(size_t)b * BCAP + gp] = pack;
        }
    }
    __syncthreads();

    for (int key = tid; key < NBH; key += 256) {
        int k = scnt[key]; if (k > BSLOTS) k = BSLOTS;
        if (k > 0) {
            const int b = key + half * NBH;
            int base2 = atomicAdd(&gcur[b], k);
            for (int i = 0; i < k; ++i)
                if (base2 + i < BCAP)
                    edges_tmp[(size_t)b * BCAP + base2 + i] = stage[key][i];
        }
    }
}

// ---------------------------------------------------------------------------
// Agg: one block per 8-row octant chunk. Single-pass scatter into 16
// fixed-stride LDS seg-lists (seg = (rowLocal&7)*2 + rel), then per-seg
// register gather from Xb; bf16 agg store. Static m204 XCD swizzle.
// ---------------------------------------------------------------------------
__global__ __launch_bounds__(256) void agg_kernel(
    const int* __restrict__ gcur,
    const unsigned long long* __restrict__ edges_tmp,
    const unsigned short* __restrict__ Xb,
    unsigned short* __restrict__ agg, int n)
{
    __shared__ unsigned long long lists[16 * SCAP];
    __shared__ int cnt[16];

    const int NQ = (n + 7) >> 3;             // 6250 chunks
    // m204 bijective XCD swizzle: consecutive swz (same bucket's octants)
    // land on the same XCD -> bucket edge list re-reads are L2-local.
    const int orig = blockIdx.x;
    const int xcd = orig & 7, bi = orig >> 3;
    const int q8 = NQ >> 3, r8 = NQ & 7;
    const int swz = (xcd < r8) ? xcd * (q8 + 1) + bi
                               : r8 * (q8 + 1) + (xcd - r8) * q8 + bi;
    if (swz >= NQ) return;

    const int b   = swz >> 3;
    const int oct = swz & 7;
    const int rowbase = swz * 8;             // = b*64 + oct*8
    const int tid = threadIdx.x;

    int sz = gcur[b]; if (sz > BCAP) sz = BCAP;
    const unsigned long long* ebase = edges_tmp + (size_t)b * BCAP;

    if (tid < 16) cnt[tid] = 0;
    __syncthreads();

    // Single pass: filter octant, append to per-seg list.
    for (int e = tid; e < sz; e += 256) {
        const unsigned long long p = ebase[e];
        const unsigned lo = (unsigned)p;
        const int rl = (int)(lo & 63u);
        if ((rl >> 3) == oct) {
            const int seg = ((rl & 7) << 1) | ((lo >> 6) & 1);
            const int pos = atomicAdd(&cnt[seg], 1);
            if (pos < SCAP) lists[seg * SCAP + pos] = p;
        }
    }
    __syncthreads();

    // Gather: 8 groups x 32 lanes; lane owns a 4-col slice (8B of bf16).
    // Edge packs via LDS broadcast (uniform addr per group); unroll x4 keeps
    // 4 independent Xb row-loads in flight. Accumulate fp32, store bf16.
    const int lane = tid & 31;
    const int grp  = tid >> 5;
    for (int seg = grp; seg < 16; seg += 8) {
        const int row = rowbase + (seg >> 1);
        if (row >= n) continue;
        const int rel = seg & 1;
        int m = cnt[seg]; if (m > SCAP) m = SCAP;
        const unsigned long long* lst = &lists[seg * SCAP];
        float4 acc = make_float4(0.f, 0.f, 0.f, 0.f);

        int e = 0;
        for (; e + 4 <= m; e += 4) {
            const unsigned long long p0 = lst[e + 0];
            const unsigned long long p1 = lst[e + 1];
            const unsigned long long p2 = lst[e + 2];
            const unsigned long long p3 = lst[e + 3];
            const ushort4 x0 = *(const ushort4*)&Xb[(size_t)(((unsigned)p0 >> 7) & 0xFFFFu) * 128 + lane * 4];
            const ushort4 x1 = *(const ushort4*)&Xb[(size_t)(((unsigned)p1 >> 7) & 0xFFFFu) * 128 + lane * 4];
            const ushort4 x2 = *(const ushort4*)&Xb[(size_t)(((unsigned)p2 >> 7) & 0xFFFFu) * 128 + lane * 4];
            const ushort4 x3 = *(const ushort4*)&Xb[(size_t)(((unsigned)p3 >> 7) & 0xFFFFu) * 128 + lane * 4];
            const float v0 = __uint_as_float((unsigned)(p0 >> 32));
            const float v1 = __uint_as_float((unsigned)(p1 >> 32));
            const float v2 = __uint_as_float((unsigned)(p2 >> 32));
            const float v3 = __uint_as_float((unsigned)(p3 >> 32));
            acc.x = fmaf(v0, __uint_as_float((unsigned)x0.x << 16), acc.x);
            acc.y = fmaf(v0, __uint_as_float((unsigned)x0.y << 16), acc.y);
            acc.z = fmaf(v0, __uint_as_float((unsigned)x0.z << 16), acc.z);
            acc.w = fmaf(v0, __uint_as_float((unsigned)x0.w << 16), acc.w);
            acc.x = fmaf(v1, __uint_as_float((unsigned)x1.x << 16), acc.x);
            acc.y = fmaf(v1, __uint_as_float((unsigned)x1.y << 16), acc.y);
            acc.z = fmaf(v1, __uint_as_float((unsigned)x1.z << 16), acc.z);
            acc.w = fmaf(v1, __uint_as_float((unsigned)x1.w << 16), acc.w);
            acc.x = fmaf(v2, __uint_as_float((unsigned)x2.x << 16), acc.x);
            acc.y = fmaf(v2, __uint_as_float((unsigned)x2.y << 16), acc.y);
            acc.z = fmaf(v2, __uint_as_float((unsigned)x2.z << 16), acc.z);
            acc.w = fmaf(v2, __uint_as_float((unsigned)x2.w << 16), acc.w);
            acc.x = fmaf(v3, __uint_as_float((unsigned)x3.x << 16), acc.x);
            acc.y = fmaf(v3, __uint_as_float((unsigned)x3.y << 16), acc.y);
            acc.z = fmaf(v3, __uint_as_float((unsigned)x3.z << 16), acc.z);
            acc.w = fmaf(v3, __uint_as_float((unsigned)x3.w << 16), acc.w);
        }
        for (; e < m; ++e) {
            const unsigned long long p = lst[e];
            const ushort4 xv = *(const ushort4*)&Xb[(size_t)(((unsigned)p >> 7) & 0xFFFFu) * 128 + lane * 4];
            const float v  = __uint_as_float((unsigned)(p >> 32));
            acc.x = fmaf(v, __uint_as_float((unsigned)xv.x << 16), acc.x);
            acc.y = fmaf(v, __uint_as_float((unsigned)xv.y << 16), acc.y);
            acc.z = fmaf(v, __uint_as_float((unsigned)xv.z << 16), acc.z);
            acc.w = fmaf(v, __uint_as_float((unsigned)xv.w << 16), acc.w);
        }

        ushort4 o;
        o.x = f2bf(acc.x); o.y = f2bf(acc.y); o.z = f2bf(acc.z); o.w = f2bf(acc.w);
        *(ushort4*)&agg[((size_t)rel * n + row) * 128 + lane * 4] = o;
    }
}

// ---------------------------------------------------------------------------
// GEMM epilogue: out = relu( agg0 @ W1 + agg1 @ W2 ), bf16 MFMA, fp32 out.
// 32-row tiles. A-frag: row = lane&15, k = (lane>>4)*8 + j. C/D: col=lane&15,
// row=(lane>>4)*4+reg  [m89-verified].
// ---------------------------------------------------------------------------
__global__ __launch_bounds__(256) void gemm_relu_kernel(
    const unsigned short* __restrict__ agg,
    const unsigned short* __restrict__ Wt,
    float* __restrict__ out, int n)
{
    const int lane = threadIdx.x & 63;
    const int w    = threadIdx.x >> 6;
    const int colbase = w * 32;
    const int l15 = lane & 15;
    const int lhi = lane >> 4;

    bf16x8 bfrag[2][2][4];                   // [rel][ct][ks]
    #pragma unroll
    for (int rel = 0; rel < 2; ++rel) {
        const unsigned short* Wr = Wt + rel * 16384;
        #pragma unroll
        for (int ct = 0; ct < 2; ++ct) {
            const int o = colbase + ct * 16 + l15;
            #pragma unroll
            for (int ks = 0; ks < 4; ++ks)
                bfrag[rel][ct][ks] = *(const bf16x8*)&Wr[o * 128 + ks * 32 + lhi * 8];
        }
    }

    const int row0 = blockIdx.x * 32;
    const f32x4 zero = {0.f, 0.f, 0.f, 0.f};

    #pragma unroll
    for (int rt = 0; rt < 2; ++rt) {
        const int r0 = row0 + rt * 16;
        int ra = r0 + l15; if (ra >= n) ra = n - 1;   // clamp OOB reads
        bf16x8 af0[4], af1[4];
        #pragma unroll
        for (int ks = 0; ks < 4; ++ks) {
            af0[ks] = *(const bf16x8*)&agg[(size_t)ra * 128 + ks * 32 + lhi * 8];
            af1[ks] = *(const bf16x8*)&agg[((size_t)n + ra) * 128 + ks * 32 + lhi * 8];
        }

        f32x4 acc[2];
        acc[0] = zero; acc[1] = zero;
        #pragma unroll
        for (int ks = 0; ks < 4; ++ks) {
            acc[0] = __builtin_amdgcn_mfma_f32_16x16x32_bf16(af0[ks], bfrag[0][0][ks], acc[0], 0, 0, 0);
            acc[1] = __builtin_amdgcn_mfma_f32_16x16x32_bf16(af0[ks], bfrag[0][1][ks], acc[1], 0, 0, 0);
            acc[0] = __builtin_amdgcn_mfma_f32_16x16x32_bf16(af1[ks], bfrag[1][0][ks], acc[0], 0, 0, 0);
            acc[1] = __builtin_amdgcn_mfma_f32_16x16x32_bf16(af1[ks], bfrag[1][1][ks], acc[1], 0, 0, 0);
        }

        #pragma unroll
        for (int ct = 0; ct < 2; ++ct) {
            const int col = colbase + ct * 16 + l15;
            #pragma unroll
            for (int j = 0; j < 4; ++j) {
                const int r = r0 + lhi * 4 + j;
                if (r < n) out[(size_t)r * 128 + col] = fmaxf(acc[ct][j], 0.f);
            }
        }
    }
}

extern "C" void kernel_launch(void* const* d_in, const int* in_sizes, int n_in,
                              void* d_out, int out_size, void* d_ws, size_t ws_size,
                              hipStream_t stream)
{
    const float* X  = (const float*)d_in[0];
    const int*   r1 = (const int*)  d_in[1];
    const int*   c1 = (const int*)  d_in[2];
    const float* v1 = (const float*)d_in[3];
    const int*   r2 = (const int*)  d_in[4];
    const int*   c2 = (const int*)  d_in[5];
    const float* v2 = (const float*)d_in[6];
    const float* W1 = (const float*)d_in[7];
    const float* W2 = (const float*)d_in[8];
    float*       out = (float*)d_out;

    const int n = in_sizes[0] / 128;   // 50000
    const int E = in_sizes[1];         // 800000

    // Workspace layout:
    //   agg       : 2*n*128 bf16   (25.6 MB)
    //   Xb        : n*128 bf16     (12.8 MB)
    //   Wt        : 2*128*128 bf16 (64 KB)
    //   edges_tmp : NB*BCAP u64    (16.0 MB), 256B-aligned
    //   gcur      : NB ints
    unsigned short* agg = (unsigned short*)d_ws;
    unsigned short* Xb  = agg + (size_t)2 * n * 128;
    unsigned short* Wt  = Xb + (size_t)n * 128;
    unsigned long long* edges_tmp =
        (unsigned long long*)(((uintptr_t)(Wt + 2 * 128 * 128) + 255) & ~(uintptr_t)255);
    int* gcur = (int*)(edges_tmp + (size_t)NB * BCAP);

    hipMemsetAsync(gcur, 0, NB * sizeof(int), stream);

    // bin + convert (fused, disjoint block ranges)
    convbin_kernel<<<BING + CONVG, 256, 0, stream>>>(
        X, W1, W2, r1, c1, v1, r2, c2, v2, Xb, Wt, gcur, edges_tmp, E, n);

    // aggregate (one block per 8-row octant chunk, static swizzle)
    agg_kernel<<<(n + 7) / 8, 256, 0, stream>>>(gcur, edges_tmp, Xb, agg, n);

    // GEMM + ReLU epilogue
    gemm_relu_kernel<<<(n + 31) / 32, 256, 0, stream>>>(agg, Wt, out, n);
}